// Round 1
// baseline (191.752 us; speedup 1.0000x reference)
//
#include <hip/hip_runtime.h>
#include <cmath>

#define MASKSZ 17
#define NPIX   289          // 17*17
#define NU     10           // unique GLCM offsets (12 slots, 2 dups)
#define NF     70           // 4 stat + 6 hist + 60 glcm
#define NWX    60
#define BATCH  8
#define IMG_W  256
#define IMG_HW 65536
#define NWIN   28800        // 8 * 60 * 60
#define ACC    560          // BATCH * NF

// slot -> unique offset index for the 12 reference offsets
__device__ __constant__ int c_s2u[12] = {0,1,2,3,4,1,5,3,6,7,8,9};

__device__ __forceinline__ float wsum(float v){ for(int o=32;o;o>>=1) v += __shfl_xor(v,o,64); return v; }
__device__ __forceinline__ int   wsumi(int v){ for(int o=32;o;o>>=1) v += __shfl_xor(v,o,64); return v; }
__device__ __forceinline__ float wmax(float v){ for(int o=32;o;o>>=1) v = fmaxf(v,__shfl_xor(v,o,64)); return v; }
__device__ __forceinline__ float wmin(float v){ for(int o=32;o;o>>=1) v = fminf(v,__shfl_xor(v,o,64)); return v; }

__global__ __launch_bounds__(64) void feat_kernel(const float* __restrict__ x,
                                                  float* __restrict__ ptot,
                                                  float* __restrict__ pnz,
                                                  int setmask) {
    __shared__ unsigned qs[NPIX];
    __shared__ unsigned cnt[64 * NU];     // [bin(i*8+j)][uniq-offset], offset contiguous
    __shared__ float    uf[5][NU];        // contrast, homog, energy, corr, entropy
    __shared__ float    s10[10];          // mean, std, f2, f3, hist1..6

    const int lane = threadIdx.x;
    const int widx = blockIdx.x;
    const int b    = widx / 3600;
    const int rem  = widx - b * 3600;
    const int wy   = rem / NWX;
    const int wx   = rem - wy * NWX;
    const float* img = x + (size_t)(b * 3 + 1) * IMG_HW + (wy * 4) * IMG_W + wx * 4;

    // zero GLCM histograms
    for (int t = lane; t < 64 * NU; t += 64) cnt[t] = 0u;

    // ---- pass A: load pixels, threshold, quantize, local stats ----
    float v[5];
    float lsum = 0.f, lmax = -1e30f, lmin = 1e30f;
    int lcnt = 0;
    int h1 = 0, h2 = 0, h3 = 0, h4 = 0, h5 = 0, h6 = 0;
#pragma unroll
    for (int k = 0; k < 5; ++k) {
        int t = lane + k * 64;
        float val = 0.f;
        if (t < NPIX) {
            int r = t / 17;
            int c = t - r * 17;
            float p = img[r * IMG_W + c];
            val = (p < 10.f) ? 0.f : p;
            unsigned qq = 0u;
            if (val != 0.f) {
                qq = 1u + (unsigned)(val >= 47.5f) + (unsigned)(val >= 87.5f)
                        + (unsigned)(val >= 127.5f) + (unsigned)(val >= 167.5f)
                        + (unsigned)(val >= 207.5f) + (unsigned)(val >= 247.5f);
                lsum += val;
                lcnt += 1;
                lmax = fmaxf(lmax, val);
                lmin = fminf(lmin, val);
                h1 += (qq == 1u); h2 += (qq == 2u); h3 += (qq == 3u);
                h4 += (qq == 4u); h5 += (qq == 5u); h6 += (qq == 6u);
            }
            qs[t] = qq;
        }
        v[k] = val;
    }
    __syncthreads();

    const int n = wsumi(lcnt);
    if (n == 0) return;   // all-zero window: feats forced to 0 in ref -> contributes nothing

    const float sum = wsum(lsum);
    const float mx  = wmax(lmax);
    const float mn  = wmin(lmin);
    const int c1 = wsumi(h1), c2 = wsumi(h2), c3 = wsumi(h3);
    const int c4 = wsumi(h4), c5 = wsumi(h5), c6 = wsumi(h6);
    const float n_safe = fmaxf((float)n, 1.f);
    const float mean = sum / n_safe;

    // ---- pass B: two-pass std (pixels kept in registers) ----
    float lss = 0.f;
#pragma unroll
    for (int k = 0; k < 5; ++k) {
        if (v[k] != 0.f) { float d = v[k] - mean; lss += d * d; }
    }
    const float stdv = sqrtf(wsum(lss) / n_safe);

    if (lane == 0) {
        s10[0] = mean;
        s10[1] = stdv;
        s10[2] = (mx - mean) / (stdv + 1e-9f);
        s10[3] = (mean - mn) / (stdv + 1e-9f);
        s10[4] = (float)c1 * (1.f / 289.f);
        s10[5] = (float)c2 * (1.f / 289.f);
        s10[6] = (float)c3 * (1.f / 289.f);
        s10[7] = (float)c4 * (1.f / 289.f);
        s10[8] = (float)c5 * (1.f / 289.f);
        s10[9] = (float)c6 * (1.f / 289.f);
    }

    // ---- GLCM pair counting: 10 unique offsets, LDS atomics ----
    {
        constexpr int DRu[NU] = {0, 1, 1, 1, 0, 2, 0, 2, 3, 2};
        constexpr int DCu[NU] = {1, 1, 0,-1, 2, 0, 3, 2, 0,-2};
#pragma unroll
        for (int o = 0; o < NU; ++o) {
            const int dr = DRu[o], dc = DCu[o];
            const int tot  = (17 - dr) * 17;    // flat index t == r*17 + c
            const int joff = dr * 17 + dc;
            for (int t = lane; t < tot; t += 64) {
                int c  = t % 17;
                int cc = c + dc;
                if (cc >= 0 && cc < 17) {
                    unsigned qi = qs[t];
                    unsigned qj = qs[t + joff];
                    atomicAdd(&cnt[(qi * 8u + qj) * NU + o], 1u);
                }
            }
        }
    }
    __syncthreads();

    // ---- per-offset features: lane o handles unique offset o (7x7 submatrix) ----
    if (lane < NU) {
        const int o = lane;
        // 1/(2*npairs) per unique offset: pairs = (17-dr)*(17-|dc|)
        constexpr float INV2N[NU] = {1.f/544.f, 1.f/512.f, 1.f/544.f, 1.f/512.f, 1.f/510.f,
                                     1.f/510.f, 1.f/476.f, 1.f/450.f, 1.f/476.f, 1.f/450.f};
        const float inv2n = INV2N[o];

        // single pass, unnormalized accumulation (scale by 1/gsum at end)
        float gsum = 0.f, ent = 0.f;
        float conU = 0.f, homU = 0.f, g2 = 0.f;
        float siU = 0.f, siiU = 0.f, sijU = 0.f;
#pragma unroll
        for (int i = 1; i < 8; ++i) {
#pragma unroll
            for (int j = 1; j < 8; ++j) {
                unsigned cc2 = cnt[(i * 8 + j) * NU + o] + cnt[(j * 8 + i) * NU + o];
                float g = (float)cc2 * inv2n;            // symmetrized, /(2*npairs)
                gsum += g;
                ent  -= g * __log2f(g + 1e-8f);          // entropy uses g (pre-renorm)
                const float fi = (float)(i - 1), fj = (float)(j - 1);
                const float d  = fi - fj;
                const float d2 = d * d;
                conU += g * d2;
                homU += g * (1.f / (1.f + d2));
                g2   += g * g;
                siU  += g * fi;
                siiU += g * fi * fi;
                sijU += g * fi * fj;
            }
        }
        const float invg = 1.f / fmaxf(gsum, 1e-12f);
        const float con = conU * invg;
        const float hom = homU * invg;
        const float energy = sqrtf(g2 * invg * invg);
        // symmetric P => Pi==Pj exactly: si==sj, sii==sjj
        const float si  = siU * invg;
        const float sii = siiU * invg;
        const float sij = sijU * invg;
        const float var = sii - si * si;
        const float sd  = sqrtf(fmaxf(var, 0.f));
        const float sdp = sd * sd;                        // sdi*sdj
        const float cov = sij - si * si;                  // sij - si*sj
        const float corr = (sdp < 1e-15f) ? 1.f : cov / fmaxf(sdp, 1e-15f);
        uf[0][o] = con;
        uf[1][o] = hom;
        uf[2][o] = energy;
        uf[3][o] = corr;
        uf[4][o] = ent;
    }
    __syncthreads();

    // ---- accumulate into partial sets (contention / nset) ----
    const int setbase = (widx & setmask) * ACC;
    const int obase   = b * NF;
    for (int t = lane; t < NF; t += 64) {
        float f;
        if (t < 10) {
            f = s10[t];
        } else {
            int u    = t - 10;
            int grp  = u / 12;          // 0=contrast 1=homog 2=energy 3=corr 4=entropy
            int slot = u - grp * 12;
            f = uf[grp][c_s2u[slot]];
        }
        atomicAdd(&ptot[setbase + obase + t], f);
        if (f != 0.f) atomicAdd(&pnz[setbase + obase + t], 1.f);
    }
}

__global__ void reduce_kernel(const float* __restrict__ ptot,
                              const float* __restrict__ pnz,
                              float* __restrict__ out, int nset) {
    int t = blockIdx.x * blockDim.x + threadIdx.x;
    if (t >= ACC) return;
    float s = 0.f, nz = 0.f;
    for (int k = 0; k < nset; ++k) {
        s  += ptot[(size_t)k * ACC + t];
        nz += pnz[(size_t)k * ACC + t];
    }
    out[t] = s / (nz + 1e-9f);
}

extern "C" void kernel_launch(void* const* d_in, const int* in_sizes, int n_in,
                              void* d_out, int out_size, void* d_ws, size_t ws_size,
                              hipStream_t stream) {
    (void)in_sizes; (void)n_in; (void)out_size;
    const float* x = (const float*)d_in[0];
    float* out = (float*)d_out;

    // partial accumulator sets in workspace: [nset][560] totals, then [nset][560] nz
    const size_t per_set = (size_t)2 * ACC * sizeof(float);   // 4480 B
    int maxs = (ws_size >= per_set) ? (int)(ws_size / per_set) : 1;
    int nset = 1;
    while ((nset * 2) <= maxs && nset < 64) nset <<= 1;

    float* ptot = (float*)d_ws;
    float* pnz  = ptot + (size_t)nset * ACC;

    hipMemsetAsync(d_ws, 0, (size_t)nset * per_set, stream);
    feat_kernel<<<dim3(NWIN), dim3(64), 0, stream>>>(x, ptot, pnz, nset - 1);
    reduce_kernel<<<dim3((ACC + 255) / 256), dim3(256), 0, stream>>>(ptot, pnz, out, nset);
}

// Round 2
// 132.909 us; speedup vs baseline: 1.4427x; 1.4427x over previous
//
#include <hip/hip_runtime.h>
#include <cmath>

#define NPIX   289          // 17*17
#define NU     10           // unique GLCM offsets (12 slots, 2 dups)
#define NF     70           // 4 stat + 6 hist + 60 glcm
#define NWX    60
#define IMG_W  256
#define IMG_HW 65536
#define NWIN   28800        // 8 * 60 * 60
#define ACC    560          // BATCH * NF
#define WPB    4            // waves (windows) per block
#define NBLK   (NWIN / WPB) // 7200

// slot -> unique offset index for the 12 reference offsets
__device__ __constant__ int c_s2u[12] = {0,1,2,3,4,1,5,3,6,7,8,9};

// unique offsets (dr, dc); flat-shift joff = dr*17 + dc
constexpr int DRu[NU] = {0, 1, 1, 1, 0, 2, 0, 2, 3, 2};
constexpr int DCu[NU] = {1, 1, 0,-1, 2, 0, 3, 2, 0,-2};
constexpr int JOFF[NU] = {1, 18, 17, 16, 2, 34, 3, 36, 51, 32};
// 1/(2*npairs), npairs = (17-dr)*(17-|dc|)
constexpr float INV2N[NU] = {1.f/544.f, 1.f/512.f, 1.f/544.f, 1.f/512.f, 1.f/510.f,
                             1.f/510.f, 1.f/476.f, 1.f/450.f, 1.f/476.f, 1.f/450.f};

// validity bitmap per offset: bit t set iff pair (t, t+joff) is in-window
struct VTab { unsigned w[NU][10]; };
constexpr VTab make_vtab() {
    VTab t{};
    for (int o = 0; o < NU; ++o)
        for (int idx = 0; idx < NPIX; ++idx) {
            int r = idx / 17, c = idx % 17, cc = c + DCu[o];
            if (r + DRu[o] <= 16 && cc >= 0 && cc <= 16)
                t.w[o][idx >> 5] |= 1u << (idx & 31);
        }
    return t;
}
constexpr VTab c_vt = make_vtab();

__device__ __forceinline__ float wsum(float v){ for(int o=32;o;o>>=1) v += __shfl_xor(v,o,64); return v; }
__device__ __forceinline__ float wmax(float v){ for(int o=32;o;o>>=1) v = fmaxf(v,__shfl_xor(v,o,64)); return v; }
__device__ __forceinline__ float wmin(float v){ for(int o=32;o;o>>=1) v = fminf(v,__shfl_xor(v,o,64)); return v; }
__device__ __forceinline__ unsigned long long wsumull(unsigned long long v){
    for (int o=32;o;o>>=1) v += __shfl_xor(v,o,64); return v;
}

__global__ __launch_bounds__(256) void feat_kernel(const float* __restrict__ x,
                                                   float* __restrict__ ptot,
                                                   float* __restrict__ pnz,
                                                   int setmask) {
    __shared__ float s_g[WPB][NU * 49];
    __shared__ float s_uf[WPB][5][NU];
    __shared__ float s_s10[WPB][10];

    const int lane = threadIdx.x & 63;
    const int wid  = threadIdx.x >> 6;
    const int widx = blockIdx.x * WPB + wid;
    const int b    = widx / 3600;
    const int rem  = widx - b * 3600;
    const int wy   = rem / NWX;
    const int wx   = rem - wy * NWX;
    const float* img = x + (size_t)(b * 3 + 1) * IMG_HW + (wy * 4) * IMG_W + wx * 4;

    float* gl  = s_g[wid];
    float (*uf)[NU] = s_uf[wid];
    float* s10 = s_s10[wid];

    // ---- pass A: load pixels, threshold, quantize, local stats ----
    float v[5]; int q[5];
    float lsum = 0.f, lmax = -1e30f, lmin = 1e30f;
    unsigned long long hpack = 0ull;   // 9-bit fields: c1..c6 at 9*(i-1), nonzero-count at bit 54
#pragma unroll
    for (int k = 0; k < 5; ++k) {
        const int t = lane + k * 64;
        float val = 0.f;
        int qq = 0;
        if (t < NPIX) {
            int r = t / 17;
            int c = t - r * 17;
            float p = img[r * IMG_W + c];
            val = (p < 10.f) ? 0.f : p;
            if (val != 0.f) {
                qq = 1 + (val >= 47.5f) + (val >= 87.5f) + (val >= 127.5f)
                       + (val >= 167.5f) + (val >= 207.5f) + (val >= 247.5f);
                lsum += val;
                lmax = fmaxf(lmax, val);
                lmin = fminf(lmin, val);
                if (qq <= 6) hpack += 1ull << (9 * (qq - 1));
                hpack += 1ull << 54;
            }
        }
        v[k] = val; q[k] = qq;
    }

    const unsigned long long hp = wsumull(hpack);
    const int n = (int)(hp >> 54) & 511;
    if (n == 0) return;   // all-zero window contributes nothing (no barriers in this kernel)

    const float sum = wsum(lsum);
    const float mx  = wmax(lmax);
    const float mn  = wmin(lmin);
    const float mean = sum / (float)n;

    // two-pass std (pixels in registers)
    float lss = 0.f;
#pragma unroll
    for (int k = 0; k < 5; ++k)
        if (v[k] != 0.f) { float d = v[k] - mean; lss += d * d; }
    const float stdv = sqrtf(wsum(lss) / (float)n);

    if (lane == 0) {
        s10[0] = mean;
        s10[1] = stdv;
        s10[2] = (mx - mean) / (stdv + 1e-9f);
        s10[3] = (mean - mn) / (stdv + 1e-9f);
#pragma unroll
        for (int i = 0; i < 6; ++i)
            s10[4 + i] = (float)((hp >> (9 * i)) & 511) * (1.f / 289.f);
    }

    // ---- bit-plane bitmaps via ballot; lane (a,b) builds Ma, Mb ----
    const int l49 = (lane < 49) ? lane : 48;
    const int ba  = l49 / 7 + 1;       // 1..7
    const int bb  = l49 - (ba - 1) * 7 + 1;
    unsigned ma32[10], mb32[12];
#pragma unroll
    for (int k = 0; k < 5; ++k) {
        unsigned long long p0 = __ballot(q[k] & 1);
        unsigned long long p1 = __ballot(q[k] & 2);
        unsigned long long p2 = __ballot(q[k] & 4);
        unsigned long long mA = ((ba & 1) ? p0 : ~p0) & ((ba & 2) ? p1 : ~p1) & ((ba & 4) ? p2 : ~p2);
        unsigned long long mB = ((bb & 1) ? p0 : ~p0) & ((bb & 2) ? p1 : ~p1) & ((bb & 4) ? p2 : ~p2);
        ma32[2*k]   = (unsigned)mA;  ma32[2*k+1] = (unsigned)(mA >> 32);
        mb32[2*k]   = (unsigned)mB;  mb32[2*k+1] = (unsigned)(mB >> 32);
    }
    mb32[10] = 0u; mb32[11] = 0u;

    // ---- GLCM counts: popcount(Ma & (Mb >> joff) & V_o) ----
    int cnta[NU];
#pragma unroll
    for (int o = 0; o < NU; ++o) {
        const int wq = JOFF[o] >> 5;
        const int r  = JOFF[o] & 31;
        int acc = 0;
#pragma unroll
        for (int w = 0; w < 10; ++w) {
            unsigned mav = ma32[w] & c_vt.w[o][w];          // constexpr-folded; zero words pruned
            unsigned sh  = (r == 0) ? mb32[w + wq]
                 : (unsigned)(((((unsigned long long)mb32[w + wq + 1]) << 32) | mb32[w + wq]) >> r);
            acc += __popc(mav & sh);
        }
        cnta[o] = acc;
    }

    // ---- symmetrize via shuffle, stage g into LDS ----
    const int partner = (bb - 1) * 7 + (ba - 1);   // transpose lane within 49
#pragma unroll
    for (int o = 0; o < NU; ++o) {
        int pc = __shfl(cnta[o], partner, 64);
        float g = (float)(cnta[o] + pc) * INV2N[o];
        if (lane < 49) gl[o * 49 + l49] = g;
    }

    // ---- features: 4 sub-lanes per offset, shfl-reduce ----
    const int fo  = lane & 15;   // offset (active fo<10)
    const int sub = lane >> 4;   // 0..3
    float gsum=0.f, entU=0.f, conU=0.f, homU=0.f, g2=0.f, siU=0.f, siiU=0.f, sijU=0.f;
    if (fo < NU) {
        for (int idx = sub; idx < 49; idx += 4) {
            float g = gl[fo * 49 + idx];
            int fi = idx / 7;
            int fj = idx - fi * 7;
            float d  = (float)(fi - fj);
            float d2 = d * d;
            float ffi = (float)fi, ffj = (float)fj;
            gsum += g;
            entU += g * __log2f(g + 1e-8f);
            conU += g * d2;
            homU += g * __builtin_amdgcn_rcpf(1.f + d2);
            g2   += g * g;
            siU  += g * ffi;
            siiU += g * ffi * ffi;
            sijU += g * ffi * ffj;
        }
    }
#pragma unroll
    for (int s = 16; s <= 32; s <<= 1) {
        gsum += __shfl_xor(gsum, s, 64);  entU += __shfl_xor(entU, s, 64);
        conU += __shfl_xor(conU, s, 64);  homU += __shfl_xor(homU, s, 64);
        g2   += __shfl_xor(g2,   s, 64);  siU  += __shfl_xor(siU,  s, 64);
        siiU += __shfl_xor(siiU, s, 64);  sijU += __shfl_xor(sijU, s, 64);
    }
    if (fo < NU && sub == 0) {
        const float invg = 1.f / fmaxf(gsum, 1e-12f);
        const float si  = siU  * invg;
        const float sii = siiU * invg;
        const float sij = sijU * invg;
        const float var = fmaxf(sii - si * si, 0.f);   // == sdi*sdj (symmetric P)
        const float cov = sij - si * si;
        uf[0][fo] = conU * invg;
        uf[1][fo] = homU * invg;
        uf[2][fo] = sqrtf(g2) * invg;
        uf[3][fo] = (var < 1e-15f) ? 1.f : cov / fmaxf(var, 1e-15f);
        uf[4][fo] = -entU;
    }

    // ---- accumulate into partial sets ----
    const int setbase = (widx & setmask) * ACC;
    const int obase   = b * NF;
    for (int t = lane; t < NF; t += 64) {
        float f;
        if (t < 10) {
            f = s10[t];
        } else {
            int u    = t - 10;
            int grp  = u / 12;          // 0=contrast 1=homog 2=energy 3=corr 4=entropy
            int slot = u - grp * 12;
            f = uf[grp][c_s2u[slot]];
        }
        atomicAdd(&ptot[setbase + obase + t], f);
        if (f != 0.f) atomicAdd(&pnz[setbase + obase + t], 1.f);
    }
}

__global__ void reduce_kernel(const float* __restrict__ ptot,
                              const float* __restrict__ pnz,
                              float* __restrict__ out, int nset) {
    int t = blockIdx.x * blockDim.x + threadIdx.x;
    if (t >= ACC) return;
    float s = 0.f, nz = 0.f;
    for (int k = 0; k < nset; ++k) {
        s  += ptot[(size_t)k * ACC + t];
        nz += pnz[(size_t)k * ACC + t];
    }
    out[t] = s / (nz + 1e-9f);
}

extern "C" void kernel_launch(void* const* d_in, const int* in_sizes, int n_in,
                              void* d_out, int out_size, void* d_ws, size_t ws_size,
                              hipStream_t stream) {
    (void)in_sizes; (void)n_in; (void)out_size;
    const float* x = (const float*)d_in[0];
    float* out = (float*)d_out;

    const size_t per_set = (size_t)2 * ACC * sizeof(float);   // 4480 B
    int maxs = (ws_size >= per_set) ? (int)(ws_size / per_set) : 1;
    int nset = 1;
    while ((nset * 2) <= maxs && nset < 64) nset <<= 1;

    float* ptot = (float*)d_ws;
    float* pnz  = ptot + (size_t)nset * ACC;

    hipMemsetAsync(d_ws, 0, (size_t)nset * per_set, stream);
    feat_kernel<<<dim3(NBLK), dim3(256), 0, stream>>>(x, ptot, pnz, nset - 1);
    reduce_kernel<<<dim3((ACC + 255) / 256), dim3(256), 0, stream>>>(ptot, pnz, out, nset);
}

// Round 3
// 125.082 us; speedup vs baseline: 1.5330x; 1.0626x over previous
//
#include <hip/hip_runtime.h>
#include <cmath>

#define NPIX   289          // 17*17
#define NU     10           // unique GLCM offsets (12 slots, 2 dups)
#define NF     70           // 4 stat + 6 hist + 60 glcm
#define NWX    60
#define IMG_W  256
#define IMG_HW 65536
#define NWIN   28800        // 8 * 60 * 60
#define ACC    560          // BATCH * NF
#define WPB    4            // waves (windows) per block
#define NBLK   (NWIN / WPB) // 7200

// slot -> unique offset index for the 12 reference offsets
__device__ __constant__ int c_s2u[12] = {0,1,2,3,4,1,5,3,6,7,8,9};

// unique offsets (dr, dc); flat-shift joff = dr*17 + dc
constexpr int DRu[NU] = {0, 1, 1, 1, 0, 2, 0, 2, 3, 2};
constexpr int DCu[NU] = {1, 1, 0,-1, 2, 0, 3, 2, 0,-2};
constexpr int JOFF[NU] = {1, 18, 17, 16, 2, 34, 3, 36, 51, 32};
// 1/(2*npairs), npairs = (17-dr)*(17-|dc|)
constexpr float INV2N[NU] = {1.f/544.f, 1.f/512.f, 1.f/544.f, 1.f/512.f, 1.f/510.f,
                             1.f/510.f, 1.f/476.f, 1.f/450.f, 1.f/476.f, 1.f/450.f};

// validity bitmap per offset: bit t set iff pair (t, t+joff) is in-window
struct VTab { unsigned w[NU][10]; };
constexpr VTab make_vtab() {
    VTab t{};
    for (int o = 0; o < NU; ++o)
        for (int idx = 0; idx < NPIX; ++idx) {
            int r = idx / 17, c = idx % 17, cc = c + DCu[o];
            if (r + DRu[o] <= 16 && cc >= 0 && cc <= 16)
                t.w[o][idx >> 5] |= 1u << (idx & 31);
        }
    return t;
}
constexpr VTab c_vt = make_vtab();

__device__ __forceinline__ float wsum(float v){ for(int o=32;o;o>>=1) v += __shfl_xor(v,o,64); return v; }
__device__ __forceinline__ float wmax(float v){ for(int o=32;o;o>>=1) v = fmaxf(v,__shfl_xor(v,o,64)); return v; }
__device__ __forceinline__ float wmin(float v){ for(int o=32;o;o>>=1) v = fminf(v,__shfl_xor(v,o,64)); return v; }

__global__ __launch_bounds__(256) void feat_kernel(const float* __restrict__ x,
                                                   float* __restrict__ ptot,
                                                   float* __restrict__ pnz,
                                                   int setmask) {
    __shared__ float s_g[WPB][NU * 49];
    __shared__ float s_uf[WPB][5][NU];
    __shared__ float s_s10[WPB][10];

    const int lane = threadIdx.x & 63;
    const int wid  = threadIdx.x >> 6;
    const int widx = blockIdx.x * WPB + wid;
    const int b    = widx / 3600;
    const int rem  = widx - b * 3600;
    const int wy   = rem / NWX;
    const int wx   = rem - wy * NWX;
    const float* img = x + (size_t)(b * 3 + 1) * IMG_HW + (wy * 4) * IMG_W + wx * 4;

    float* gl  = s_g[wid];
    float (*uf)[NU] = s_uf[wid];
    float* s10 = s_s10[wid];

    // lane -> (a,b) bin pair for the GLCM phase
    const int l49 = (lane < 49) ? lane : 48;
    const int ba  = l49 / 7 + 1;       // 1..7
    const int bb  = l49 - (ba - 1) * 7 + 1;

    // ---- pass A: load, threshold, quantize(float), stats, bit-plane ballots ----
    float lsum = 0.f, lss = 0.f, lmax = -1e30f, lmin = 1e30f;
    unsigned long long p0s[5], p1s[5], p2s[5];
#pragma unroll
    for (int k = 0; k < 5; ++k) {
        const int t = lane + k * 64;
        float val = 0.f;
        if (t < NPIX) {
            const int r = t / 17;
            float p = img[r * (IMG_W - 17) + t];   // r*256 + c == r*239 + t
            val = (p < 10.f) ? 0.f : p;
        }
        // quantize: q = 1 + clamp(floor((val-47.5)/40)+1, 0, 6), q=0 for val==0
        float qf = fminf(fmaxf(floorf(fmaf(val, 0.025f, -1.1875f)) + 1.f, 0.f), 6.f);
        int qq = (val != 0.f) ? ((int)qf + 1) : 0;
        // stats (nonzero-masked)
        lsum += val;
        float d = (val != 0.f) ? (val - 127.5f) : 0.f;
        lss = fmaf(d, d, lss);
        lmax = fmaxf(lmax, val);                          // zeros can't win (max>=10)
        lmin = fminf(lmin, (val != 0.f) ? val : 1e30f);
        // bit planes (wave-uniform SGPR results)
        p0s[k] = __ballot(qq & 1);
        p1s[k] = __ballot(qq & 2);
        p2s[k] = __ballot(qq & 4);
    }

    // ---- histogram + n on the scalar pipe ----
    int n = 0, c1 = 0, c2 = 0, c3 = 0, c4 = 0, c5 = 0, c6 = 0;
#pragma unroll
    for (int k = 0; k < 5; ++k) {
        unsigned long long p0 = p0s[k], p1 = p1s[k], p2 = p2s[k];
        n  += __popcll(p0 | p1 | p2);
        c1 += __popcll(p0 & ~p1 & ~p2);
        c2 += __popcll(~p0 & p1 & ~p2);
        c3 += __popcll(p0 & p1 & ~p2);
        c4 += __popcll(~p0 & ~p1 & p2);
        c5 += __popcll(p0 & ~p1 & p2);
        c6 += __popcll(~p0 & p1 & p2);
    }
    if (n == 0) return;   // all-zero window contributes nothing (no barriers in this kernel)

    const float fn   = (float)n;
    const float sum  = wsum(lsum);
    const float ss   = wsum(lss);
    const float mx   = wmax(lmax);
    const float mn   = wmin(lmin);
    const float mean = sum / fn;
    const float mc   = mean - 127.5f;
    const float var  = fmaxf(ss / fn - mc * mc, 0.f);
    const float stdv = sqrtf(var);

    if (lane == 0) {
        s10[0] = mean;
        s10[1] = stdv;
        s10[2] = (mx - mean) / (stdv + 1e-9f);
        s10[3] = (mean - mn) / (stdv + 1e-9f);
        s10[4] = (float)c1 * (1.f / 289.f);
        s10[5] = (float)c2 * (1.f / 289.f);
        s10[6] = (float)c3 * (1.f / 289.f);
        s10[7] = (float)c4 * (1.f / 289.f);
        s10[8] = (float)c5 * (1.f / 289.f);
        s10[9] = (float)c6 * (1.f / 289.f);
    }

    // ---- per-lane bin bitmaps Ma, Mb from the uniform planes ----
    unsigned ma32[10], mb32[12];
#pragma unroll
    for (int k = 0; k < 5; ++k) {
        unsigned long long p0 = p0s[k], p1 = p1s[k], p2 = p2s[k];
        unsigned long long mA = ((ba & 1) ? p0 : ~p0) & ((ba & 2) ? p1 : ~p1) & ((ba & 4) ? p2 : ~p2);
        unsigned long long mB = ((bb & 1) ? p0 : ~p0) & ((bb & 2) ? p1 : ~p1) & ((bb & 4) ? p2 : ~p2);
        ma32[2*k]   = (unsigned)mA;  ma32[2*k+1] = (unsigned)(mA >> 32);
        mb32[2*k]   = (unsigned)mB;  mb32[2*k+1] = (unsigned)(mB >> 32);
    }
    mb32[10] = 0u; mb32[11] = 0u;

    // ---- GLCM counts: popcount(Ma & (Mb >> joff) & V_o) ----
    int cnta[NU];
#pragma unroll
    for (int o = 0; o < NU; ++o) {
        const int wq = JOFF[o] >> 5;
        const int r  = JOFF[o] & 31;
        int acc = 0;
#pragma unroll
        for (int w = 0; w < 10; ++w) {
            unsigned mav = ma32[w] & c_vt.w[o][w];          // constexpr-folded; zero words pruned
            unsigned sh  = (r == 0) ? mb32[w + wq]
                 : (unsigned)(((((unsigned long long)mb32[w + wq + 1]) << 32) | mb32[w + wq]) >> r);
            acc += __popc(mav & sh);
        }
        cnta[o] = acc;
    }

    // ---- symmetrize via shuffle, stage g into LDS ----
    const int partner = (bb - 1) * 7 + (ba - 1);   // transpose lane within 49
#pragma unroll
    for (int o = 0; o < NU; ++o) {
        int pc = __shfl(cnta[o], partner, 64);
        float g = (float)(cnta[o] + pc) * INV2N[o];
        if (lane < 49) gl[o * 49 + l49] = g;
    }

    // ---- features: 4 sub-lanes per offset, shfl-reduce ----
    const int fo  = lane & 15;   // offset (active fo<10)
    const int sub = lane >> 4;   // 0..3
    float gsum=0.f, entU=0.f, conU=0.f, homU=0.f, g2=0.f, siU=0.f, siiU=0.f, sijU=0.f;
    if (fo < NU) {
        for (int idx = sub; idx < 49; idx += 4) {
            float g = gl[fo * 49 + idx];
            int fi = (idx * 37) >> 8;        // idx/7 for idx<49
            int fj = idx - fi * 7;
            float d  = (float)(fi - fj);
            float d2 = d * d;
            float ffi = (float)fi, ffj = (float)fj;
            gsum += g;
            entU += g * __log2f(g + 1e-8f);
            conU += g * d2;
            homU += g * __builtin_amdgcn_rcpf(1.f + d2);
            g2   += g * g;
            siU  += g * ffi;
            siiU += g * ffi * ffi;
            sijU += g * ffi * ffj;
        }
    }
#pragma unroll
    for (int s = 16; s <= 32; s <<= 1) {
        gsum += __shfl_xor(gsum, s, 64);  entU += __shfl_xor(entU, s, 64);
        conU += __shfl_xor(conU, s, 64);  homU += __shfl_xor(homU, s, 64);
        g2   += __shfl_xor(g2,   s, 64);  siU  += __shfl_xor(siU,  s, 64);
        siiU += __shfl_xor(siiU, s, 64);  sijU += __shfl_xor(sijU, s, 64);
    }
    if (fo < NU && sub == 0) {
        const float invg = 1.f / fmaxf(gsum, 1e-12f);
        const float si  = siU  * invg;
        const float sii = siiU * invg;
        const float sij = sijU * invg;
        const float varg = fmaxf(sii - si * si, 0.f);   // == sdi*sdj (symmetric P)
        const float cov  = sij - si * si;
        uf[0][fo] = conU * invg;
        uf[1][fo] = homU * invg;
        uf[2][fo] = sqrtf(g2) * invg;
        uf[3][fo] = (varg < 1e-15f) ? 1.f : cov / fmaxf(varg, 1e-15f);
        uf[4][fo] = -entU;
    }

    // ---- accumulate into partial sets ----
    const int setbase = (widx & setmask) * ACC;
    const int obase   = b * NF;
    for (int t = lane; t < NF; t += 64) {
        float f;
        if (t < 10) {
            f = s10[t];
        } else {
            int u    = t - 10;
            int grp  = u / 12;          // 0=contrast 1=homog 2=energy 3=corr 4=entropy
            int slot = u - grp * 12;
            f = uf[grp][c_s2u[slot]];
        }
        atomicAdd(&ptot[setbase + obase + t], f);
        if (f != 0.f) atomicAdd(&pnz[setbase + obase + t], 1.f);
    }
}

__global__ void reduce_kernel(const float* __restrict__ ptot,
                              const float* __restrict__ pnz,
                              float* __restrict__ out, int nset) {
    int t = blockIdx.x * blockDim.x + threadIdx.x;
    if (t >= ACC) return;
    float s = 0.f, nz = 0.f;
    for (int k = 0; k < nset; ++k) {
        s  += ptot[(size_t)k * ACC + t];
        nz += pnz[(size_t)k * ACC + t];
    }
    out[t] = s / (nz + 1e-9f);
}

extern "C" void kernel_launch(void* const* d_in, const int* in_sizes, int n_in,
                              void* d_out, int out_size, void* d_ws, size_t ws_size,
                              hipStream_t stream) {
    (void)in_sizes; (void)n_in; (void)out_size;
    const float* x = (const float*)d_in[0];
    float* out = (float*)d_out;

    const size_t per_set = (size_t)2 * ACC * sizeof(float);   // 4480 B
    int maxs = (ws_size >= per_set) ? (int)(ws_size / per_set) : 1;
    int nset = 1;
    while ((nset * 2) <= maxs && nset < 64) nset <<= 1;

    float* ptot = (float*)d_ws;
    float* pnz  = ptot + (size_t)nset * ACC;

    hipMemsetAsync(d_ws, 0, (size_t)nset * per_set, stream);
    feat_kernel<<<dim3(NBLK), dim3(256), 0, stream>>>(x, ptot, pnz, nset - 1);
    reduce_kernel<<<dim3((ACC + 255) / 256), dim3(256), 0, stream>>>(ptot, pnz, out, nset);
}

// Round 4
// 122.257 us; speedup vs baseline: 1.5684x; 1.0231x over previous
//
#include <hip/hip_runtime.h>
#include <cmath>

#define NPIX   289          // 17*17
#define NU     10           // unique GLCM offsets (12 slots, 2 dups)
#define NF     70           // 4 stat + 6 hist + 60 glcm
#define NWX    60
#define IMG_W  256
#define IMG_HW 65536
#define NWIN   28800        // 8 * 60 * 60
#define ACC    560          // BATCH * NF
#define WPB    4            // waves (windows) per block
#define NBLK   (NWIN / WPB) // 7200

// slot -> unique offset index for the 12 reference offsets
__device__ __constant__ int c_s2u[12] = {0,1,2,3,4,1,5,3,6,7,8,9};

// unique offsets (dr, dc); flat-shift joff = dr*17 + dc
constexpr int DRu[NU] = {0, 1, 1, 1, 0, 2, 0, 2, 3, 2};
constexpr int DCu[NU] = {1, 1, 0,-1, 2, 0, 3, 2, 0,-2};
constexpr int JOFF[NU] = {1, 18, 17, 16, 2, 34, 3, 36, 51, 32};
// 1/(2*npairs), npairs = (17-dr)*(17-|dc|)
constexpr float INV2N[NU] = {1.f/544.f, 1.f/512.f, 1.f/544.f, 1.f/512.f, 1.f/510.f,
                             1.f/510.f, 1.f/476.f, 1.f/450.f, 1.f/476.f, 1.f/450.f};

// validity bitmap per offset: bit t set iff pair (t, t+joff) is in-window
struct VTab { unsigned w[NU][10]; };
constexpr VTab make_vtab() {
    VTab t{};
    for (int o = 0; o < NU; ++o)
        for (int idx = 0; idx < NPIX; ++idx) {
            int r = idx / 17, c = idx % 17, cc = c + DCu[o];
            if (r + DRu[o] <= 16 && cc >= 0 && cc <= 16)
                t.w[o][idx >> 5] |= 1u << (idx & 31);
        }
    return t;
}
constexpr VTab c_vt = make_vtab();

__device__ __forceinline__ float wsum(float v){ for(int o=32;o;o>>=1) v += __shfl_xor(v,o,64); return v; }
__device__ __forceinline__ float wmax(float v){ for(int o=32;o;o>>=1) v = fmaxf(v,__shfl_xor(v,o,64)); return v; }
__device__ __forceinline__ float wmin(float v){ for(int o=32;o;o>>=1) v = fminf(v,__shfl_xor(v,o,64)); return v; }

__global__ __launch_bounds__(256) void feat_kernel(const float* __restrict__ x,
                                                   float* __restrict__ ptot,
                                                   float* __restrict__ pnz,
                                                   int setmask) {
    __shared__ float s_g[WPB][NU * 49];
    __shared__ float s_uf[WPB][5][NU];
    __shared__ float s_s10[WPB][10];

    const int lane = threadIdx.x & 63;
    const int wid  = threadIdx.x >> 6;
    const int widx = blockIdx.x * WPB + wid;
    const int b    = widx / 3600;
    const int rem  = widx - b * 3600;
    const int wy   = rem / NWX;
    const int wx   = rem - wy * NWX;
    const float* img = x + (size_t)(b * 3 + 1) * IMG_HW + (wy * 4) * IMG_W + wx * 4;

    float* gl  = s_g[wid];
    float (*uf)[NU] = s_uf[wid];
    float* s10 = s_s10[wid];

    // lane -> (a,b) bin pair for the GLCM phase
    const int l49 = (lane < 49) ? lane : 48;
    const int ba  = l49 / 7 + 1;       // 1..7
    const int bb  = l49 - (ba - 1) * 7 + 1;
    // per-lane XOR masks: plane ^ xm == (bit set in bin index ? plane : ~plane)
    const unsigned long long xm0a = (ba & 1) ? 0ull : ~0ull;
    const unsigned long long xm1a = (ba & 2) ? 0ull : ~0ull;
    const unsigned long long xm2a = (ba & 4) ? 0ull : ~0ull;
    const unsigned long long xm0b = (bb & 1) ? 0ull : ~0ull;
    const unsigned long long xm1b = (bb & 2) ? 0ull : ~0ull;
    const unsigned long long xm2b = (bb & 4) ? 0ull : ~0ull;

    // ---- pass A: load, threshold, quantize, stats; ballots consumed per-k ----
    float lsum = 0.f, lss = 0.f, lmax = -1e30f, lmin = 1e30f;
    int n = 0, c1 = 0, c2 = 0, c3 = 0, c4 = 0, c5 = 0, c6 = 0;
    unsigned ma32[10], mb32[12];
#pragma unroll
    for (int k = 0; k < 5; ++k) {
        const int t = lane + k * 64;
        float val = 0.f;
        if (t < NPIX) {
            const int r = t / 17;
            float p = img[r * (IMG_W - 17) + t];   // r*256 + c == r*239 + t
            val = (p < 10.f) ? 0.f : p;
        }
        // quantize: q = 1 + clamp(floor((val-47.5)/40)+1, 0, 6), q=0 for val==0
        float qf = fminf(fmaxf(floorf(fmaf(val, 0.025f, -1.1875f)) + 1.f, 0.f), 6.f);
        int qq = (val != 0.f) ? ((int)qf + 1) : 0;
        // stats (nonzero-masked)
        lsum += val;
        float d = (val != 0.f) ? (val - 127.5f) : 0.f;
        lss = fmaf(d, d, lss);
        lmax = fmaxf(lmax, val);                          // zeros can't win (max>=10)
        lmin = fminf(lmin, (val != 0.f) ? val : 1e30f);
        // bit planes (wave-uniform) -- consumed immediately, not stored
        unsigned long long p0 = __ballot(qq & 1);
        unsigned long long p1 = __ballot(qq & 2);
        unsigned long long p2 = __ballot(qq & 4);
        // scalar-pipe histogram
        n  += __popcll(p0 | p1 | p2);
        c1 += __popcll(p0 & ~p1 & ~p2);
        c2 += __popcll(~p0 & p1 & ~p2);
        c3 += __popcll(p0 & p1 & ~p2);
        c4 += __popcll(~p0 & ~p1 & p2);
        c5 += __popcll(p0 & ~p1 & p2);
        c6 += __popcll(~p0 & p1 & p2);
        // per-lane bin bitmaps
        unsigned long long mA = (p0 ^ xm0a) & (p1 ^ xm1a) & (p2 ^ xm2a);
        unsigned long long mB = (p0 ^ xm0b) & (p1 ^ xm1b) & (p2 ^ xm2b);
        ma32[2*k]   = (unsigned)mA;  ma32[2*k+1] = (unsigned)(mA >> 32);
        mb32[2*k]   = (unsigned)mB;  mb32[2*k+1] = (unsigned)(mB >> 32);
    }
    mb32[10] = 0u; mb32[11] = 0u;

    if (n == 0) return;   // all-zero window contributes nothing (no barriers in this kernel)

    const float fn   = (float)n;
    const float sum  = wsum(lsum);
    const float ss   = wsum(lss);
    const float mx   = wmax(lmax);
    const float mn   = wmin(lmin);
    const float mean = sum / fn;
    const float mc   = mean - 127.5f;
    const float var  = fmaxf(ss / fn - mc * mc, 0.f);
    const float stdv = sqrtf(var);

    if (lane == 0) {
        s10[0] = mean;
        s10[1] = stdv;
        s10[2] = (mx - mean) / (stdv + 1e-9f);
        s10[3] = (mean - mn) / (stdv + 1e-9f);
        s10[4] = (float)c1 * (1.f / 289.f);
        s10[5] = (float)c2 * (1.f / 289.f);
        s10[6] = (float)c3 * (1.f / 289.f);
        s10[7] = (float)c4 * (1.f / 289.f);
        s10[8] = (float)c5 * (1.f / 289.f);
        s10[9] = (float)c6 * (1.f / 289.f);
    }

    // ---- GLCM counts: popcount(Ma & (Mb >> joff) & V_o) ----
    int cnta[NU];
#pragma unroll
    for (int o = 0; o < NU; ++o) {
        const int wq = JOFF[o] >> 5;
        const int r  = JOFF[o] & 31;
        int acc = 0;
#pragma unroll
        for (int w = 0; w < 10; ++w) {
            unsigned mav = ma32[w] & c_vt.w[o][w];          // constexpr-folded; zero words pruned
            unsigned sh  = __builtin_amdgcn_alignbit(mb32[w + wq + 1], mb32[w + wq], r);
            acc += __popc(mav & sh);
        }
        cnta[o] = acc;
    }

    // ---- symmetrize via shuffle, stage g into LDS ----
    const int partner = (bb - 1) * 7 + (ba - 1);   // transpose lane within 49
#pragma unroll
    for (int o = 0; o < NU; ++o) {
        int pc = __shfl(cnta[o], partner, 64);
        float g = (float)(cnta[o] + pc) * INV2N[o];
        if (lane < 49) gl[o * 49 + l49] = g;
    }

    // ---- features: 4 sub-lanes per offset, shfl-reduce ----
    const int fo  = lane & 15;   // offset (active fo<10)
    const int sub = lane >> 4;   // 0..3
    float gsum=0.f, entU=0.f, conU=0.f, homU=0.f, g2=0.f, siU=0.f, siiU=0.f, sijU=0.f;
    if (fo < NU) {
        for (int idx = sub; idx < 49; idx += 4) {
            float g = gl[fo * 49 + idx];
            int fi = (idx * 37) >> 8;        // idx/7 for idx<49
            int fj = idx - fi * 7;
            float d  = (float)(fi - fj);
            float d2 = d * d;
            float ffi = (float)fi, ffj = (float)fj;
            gsum += g;
            entU += g * __log2f(g + 1e-8f);
            conU += g * d2;
            homU += g * __builtin_amdgcn_rcpf(1.f + d2);
            g2   += g * g;
            siU  += g * ffi;
            siiU += g * ffi * ffi;
            sijU += g * ffi * ffj;
        }
    }
#pragma unroll
    for (int s = 16; s <= 32; s <<= 1) {
        gsum += __shfl_xor(gsum, s, 64);  entU += __shfl_xor(entU, s, 64);
        conU += __shfl_xor(conU, s, 64);  homU += __shfl_xor(homU, s, 64);
        g2   += __shfl_xor(g2,   s, 64);  siU  += __shfl_xor(siU,  s, 64);
        siiU += __shfl_xor(siiU, s, 64);  sijU += __shfl_xor(sijU, s, 64);
    }
    if (fo < NU && sub == 0) {
        const float invg = 1.f / fmaxf(gsum, 1e-12f);
        const float si  = siU  * invg;
        const float sii = siiU * invg;
        const float sij = sijU * invg;
        const float varg = fmaxf(sii - si * si, 0.f);   // == sdi*sdj (symmetric P)
        const float cov  = sij - si * si;
        uf[0][fo] = conU * invg;
        uf[1][fo] = homU * invg;
        uf[2][fo] = sqrtf(g2) * invg;
        uf[3][fo] = (varg < 1e-15f) ? 1.f : cov / fmaxf(varg, 1e-15f);
        uf[4][fo] = -entU;
    }

    // ---- accumulate into partial sets ----
    const int setbase = (widx & setmask) * ACC;
    const int obase   = b * NF;
    for (int t = lane; t < NF; t += 64) {
        float f;
        if (t < 10) {
            f = s10[t];
        } else {
            int u    = t - 10;
            int grp  = u / 12;          // 0=contrast 1=homog 2=energy 3=corr 4=entropy
            int slot = u - grp * 12;
            f = uf[grp][c_s2u[slot]];
        }
        if (f != 0.f) {
            atomicAdd(&ptot[setbase + obase + t], f);
            atomicAdd(&pnz[setbase + obase + t], 1.f);
        }
    }
}

__global__ void reduce_kernel(const float* __restrict__ ptot,
                              const float* __restrict__ pnz,
                              float* __restrict__ out, int nset) {
    int t = blockIdx.x * blockDim.x + threadIdx.x;
    if (t >= ACC) return;
    float s = 0.f, nz = 0.f;
    for (int k = 0; k < nset; ++k) {
        s  += ptot[(size_t)k * ACC + t];
        nz += pnz[(size_t)k * ACC + t];
    }
    out[t] = s / (nz + 1e-9f);
}

extern "C" void kernel_launch(void* const* d_in, const int* in_sizes, int n_in,
                              void* d_out, int out_size, void* d_ws, size_t ws_size,
                              hipStream_t stream) {
    (void)in_sizes; (void)n_in; (void)out_size;
    const float* x = (const float*)d_in[0];
    float* out = (float*)d_out;

    const size_t per_set = (size_t)2 * ACC * sizeof(float);   // 4480 B
    int maxs = (ws_size >= per_set) ? (int)(ws_size / per_set) : 1;
    int nset = 1;
    while ((nset * 2) <= maxs && nset < 64) nset <<= 1;

    float* ptot = (float*)d_ws;
    float* pnz  = ptot + (size_t)nset * ACC;

    hipMemsetAsync(d_ws, 0, (size_t)nset * per_set, stream);
    feat_kernel<<<dim3(NBLK), dim3(256), 0, stream>>>(x, ptot, pnz, nset - 1);
    reduce_kernel<<<dim3((ACC + 255) / 256), dim3(256), 0, stream>>>(ptot, pnz, out, nset);
}